// Round 5
// baseline (768.701 us; speedup 1.0000x reference)
//
#include <hip/hip_runtime.h>
#include <hip/hip_bf16.h>
#include <stdint.h>

// Problem constants (fixed by reference)
#define H_K   2048
#define VV    128256
#define NROWS 1024
#define SOFTCAP_F   30.0f
#define LS_EPS      0.1f
#define ZLOSS_SCALE 1e-4f
#define IGNORE_IDX  (-100)

// 256x256 tile, BK=64, 8 waves (2M x 4N), wave owns 128x64. 4-phase K-loop.
#define BM 256
#define BN 256
#define BK 64
#define NIT 32
#define THREADS 512

typedef __attribute__((ext_vector_type(8))) short bf16x8;
typedef __attribute__((ext_vector_type(4))) float f32x4;

__device__ __forceinline__ short f2bf(float f) {
    __hip_bfloat16 h = __float2bfloat16(f);
    return __builtin_bit_cast(short, h);
}
// pack hi16(lo),hi16(hi) -> one u32 (bf16 truncation; 1 v_perm_b32)
__device__ __forceinline__ unsigned pk2bf(float lo, float hi) {
    return __builtin_amdgcn_perm(__builtin_bit_cast(unsigned, hi),
                                 __builtin_bit_cast(unsigned, lo), 0x07060302u);
}
__device__ __forceinline__ void gload_lds16(const void* g, void* l) {
    __builtin_amdgcn_global_load_lds(
        (const __attribute__((address_space(1))) unsigned*)g,
        (__attribute__((address_space(3))) unsigned*)l, 16, 0, 0);
}

#define WAITVM(N) asm volatile("s_waitcnt vmcnt(" #N ")" ::: "memory")
#define WAITLG_SB do { asm volatile("s_waitcnt lgkmcnt(0)" ::: "memory"); \
                       __builtin_amdgcn_sched_barrier(0); } while (0)

// ---------------- x fp32 -> bf16 (one-time, RNE) ----------------
__global__ void cvt_x_kernel(const float* __restrict__ x, short* __restrict__ xb, int n4) {
    int i = blockIdx.x * blockDim.x + threadIdx.x;
    if (i >= n4) return;
    float4 v = ((const float4*)x)[i];
    short4 h;
    h.x = f2bf(v.x); h.y = f2bf(v.y); h.z = f2bf(v.z); h.w = f2bf(v.w);
    ((short4*)xb)[i] = h;
}

// ---------------- fused GEMM + softcap + partial reductions ----------------
// LDS: A,B each 2 x 32 KB (128 KB). Rows of 128 B, XOR-swizzle kb ^= (row&7)<<4
// (both sides: pre-swizzled gload_lds source for A, swizzled ds_write for B).
// Per iteration (1 K-step of 64): 4 phases (kk,mh), each {ds_read | stage |
// barrier | lgkm0 | 16 MFMA | barrier}. W fp32->bf16 via v_perm in reg slots:
// slot p consumed (cvt+ds_write) then reloaded each phase -> 4-phase (~2500cy)
// prefetch distance. Counted vmcnt 6/8/10/10, end-of-iter 4. Never 0 in loop.
__global__ __launch_bounds__(THREADS, 2)
void gemm_fused(const float* __restrict__ W,
                const short* __restrict__ xb,
                const int* __restrict__ y,
                float* __restrict__ ws_se,
                float* __restrict__ ws_sl,
                float* __restrict__ ws_zy)
{
    __shared__ short As[2][BM * BK];   // 2 x 32 KB
    __shared__ short Bs[2][BN * BK];   // 2 x 32 KB

    const int tid  = threadIdx.x;
    const int lane = tid & 63;
    const int wid  = tid >> 6;
    const int wm   = wid >> 2;          // 0..1
    const int wn   = wid & 3;           // 0..3

    // bijective XCD swizzle: nwg = 2004 = 8*250+4 (m204)
    const int bid  = blockIdx.x;
    const int xcd  = bid & 7, o8 = bid >> 3;
    const int work = (xcd < 4 ? xcd * 251 : 1004 + (xcd - 4) * 250) + o8;
    const int mblk = work & 3;          // 4 m-sharers consecutive per XCD
    const int nblk = work >> 2;
    const int row0 = mblk * BM;
    const int col0 = nblk * BN;

    // A staging: 4 gload_lds per iter (8 KB each), source pre-swizzled.
    // LDS byte L = q*8192 + wid*1024 + lane*16 ; row = L>>7 ; kb = (L&127)^((row&7)<<4)
    const char* asrc = (const char*)xb
        + (size_t)(row0 + wid * 8 + (lane >> 3)) * (H_K * 2)
        + (((lane & 7) * 16) ^ ((lane >> 3) << 4));
    // W source: thread covers row (tid>>3) + P*64, fp32 bytes (tid&7)*32
    const char* wsrc = (const char*)W
        + (size_t)(col0 + (tid >> 3)) * (H_K * 4) + (tid & 7) * 32;
    // B ds_write byte offset within one buffer (swizzled), + P*8192
    const int bw0 = (tid >> 3) * 128 + (((tid & 7) * 16) ^ (((tid >> 3) & 7) << 4));

    // MFMA read offsets
    const int lrow = lane & 15;
    const int lkg  = lane >> 4;
    const int key  = (lrow & 7) << 4;
    const int rbA  = (wm * 128 + lrow) * 128;
    const int rbB  = (wn * 64 + lrow) * 128;
    const int rk0  = (lkg * 16) ^ key;
    const int rk1  = (64 + lkg * 16) ^ key;

    f32x4 acc[8][4] = {};
    float4 f0a, f0b, f1a, f1b, f2a, f2b, f3a, f3b;
    bf16x8 bb0, bb1, bb2, bb3;

    // ---- prologue: stage K-step 0 into buf0; reload slots with K-step 1 ----
    {
        f0a = *(const float4*)(wsrc);                 f0b = *(const float4*)(wsrc + 16);
        f1a = *(const float4*)(wsrc +  524288);       f1b = *(const float4*)(wsrc +  524288 + 16);
        f2a = *(const float4*)(wsrc + 1048576);       f2b = *(const float4*)(wsrc + 1048576 + 16);
        f3a = *(const float4*)(wsrc + 1572864);       f3b = *(const float4*)(wsrc + 1572864 + 16);
        gload_lds16(asrc,          (char*)As + wid * 1024);
        gload_lds16(asrc + 262144, (char*)As +  8192 + wid * 1024);
        gload_lds16(asrc + 524288, (char*)As + 16384 + wid * 1024);
        gload_lds16(asrc + 786432, (char*)As + 24576 + wid * 1024);
        WAITVM(0);
        char* B0 = (char*)Bs;
        uint4 u;
        u.x = pk2bf(f0a.x, f0a.y); u.y = pk2bf(f0a.z, f0a.w);
        u.z = pk2bf(f0b.x, f0b.y); u.w = pk2bf(f0b.z, f0b.w);
        *(uint4*)(B0 + bw0)         = u;
        u.x = pk2bf(f1a.x, f1a.y); u.y = pk2bf(f1a.z, f1a.w);
        u.z = pk2bf(f1b.x, f1b.y); u.w = pk2bf(f1b.z, f1b.w);
        *(uint4*)(B0 + bw0 +  8192) = u;
        u.x = pk2bf(f2a.x, f2a.y); u.y = pk2bf(f2a.z, f2a.w);
        u.z = pk2bf(f2b.x, f2b.y); u.w = pk2bf(f2b.z, f2b.w);
        *(uint4*)(B0 + bw0 + 16384) = u;
        u.x = pk2bf(f3a.x, f3a.y); u.y = pk2bf(f3a.z, f3a.w);
        u.z = pk2bf(f3b.x, f3b.y); u.w = pk2bf(f3b.z, f3b.w);
        *(uint4*)(B0 + bw0 + 24576) = u;
        // reload slots with K-step 1
        f0a = *(const float4*)(wsrc + 256);           f0b = *(const float4*)(wsrc + 256 + 16);
        f1a = *(const float4*)(wsrc +  524288 + 256); f1b = *(const float4*)(wsrc +  524288 + 256 + 16);
        f2a = *(const float4*)(wsrc + 1048576 + 256); f2b = *(const float4*)(wsrc + 1048576 + 256 + 16);
        f3a = *(const float4*)(wsrc + 1572864 + 256); f3b = *(const float4*)(wsrc + 1572864 + 256 + 16);
        asm volatile("s_waitcnt lgkmcnt(0)" ::: "memory");
        __builtin_amdgcn_s_barrier();
    }

#define MFM(mi,ni,AF,BV) acc[mi][ni] = __builtin_amdgcn_mfma_f32_16x16x32_bf16(AF, BV, acc[mi][ni], 0, 0, 0)

#define PH(CUR,KK,MH,P,RB,FA,FB,ISSA,ISSW,DOCVT,WVN,EVN,J) do { \
    const char* Ab_ = ((const char*)As) + (CUR) * 32768; \
    const char* Bb_ = ((const char*)Bs) + (CUR) * 32768; \
    if (RB) { \
        bb0 = *(const bf16x8*)(Bb_ + rbB +    0 + rk##KK); \
        bb1 = *(const bf16x8*)(Bb_ + rbB + 2048 + rk##KK); \
        bb2 = *(const bf16x8*)(Bb_ + rbB + 4096 + rk##KK); \
        bb3 = *(const bf16x8*)(Bb_ + rbB + 6144 + rk##KK); \
    } \
    bf16x8 a0_ = *(const bf16x8*)(Ab_ + rbA + (MH)*8192 +    0 + rk##KK); \
    bf16x8 a1_ = *(const bf16x8*)(Ab_ + rbA + (MH)*8192 + 2048 + rk##KK); \
    bf16x8 a2_ = *(const bf16x8*)(Ab_ + rbA + (MH)*8192 + 4096 + rk##KK); \
    bf16x8 a3_ = *(const bf16x8*)(Ab_ + rbA + (MH)*8192 + 6144 + rk##KK); \
    WAITVM(WVN); \
    if (DOCVT) { \
        uint4 u_; \
        u_.x = pk2bf(FA.x, FA.y); u_.y = pk2bf(FA.z, FA.w); \
        u_.z = pk2bf(FB.x, FB.y); u_.w = pk2bf(FB.z, FB.w); \
        *(uint4*)(((char*)Bs) + ((CUR)^1) * 32768 + bw0 + (P) * 8192) = u_; \
    } \
    if (ISSW) { \
        FA = *(const float4*)(wsrc + (P) * 524288 + (size_t)((J)+2) * 256); \
        FB = *(const float4*)(wsrc + (P) * 524288 + (size_t)((J)+2) * 256 + 16); \
    } \
    if (ISSA) { \
        gload_lds16(asrc + ((P)*2  ) * 262144 + (size_t)((J)+1) * 128, \
                    (char*)As + ((CUR)^1) * 32768 + ((P)*2  ) * 8192 + wid * 1024); \
        gload_lds16(asrc + ((P)*2+1) * 262144 + (size_t)((J)+1) * 128, \
                    (char*)As + ((CUR)^1) * 32768 + ((P)*2+1) * 8192 + wid * 1024); \
    } \
    __builtin_amdgcn_s_barrier(); \
    WAITLG_SB; \
    __builtin_amdgcn_s_setprio(1); \
    MFM((MH)*4+0,0,a0_,bb0); MFM((MH)*4+0,1,a0_,bb1); MFM((MH)*4+0,2,a0_,bb2); MFM((MH)*4+0,3,a0_,bb3); \
    MFM((MH)*4+1,0,a1_,bb0); MFM((MH)*4+1,1,a1_,bb1); MFM((MH)*4+1,2,a1_,bb2); MFM((MH)*4+1,3,a1_,bb3); \
    MFM((MH)*4+2,0,a2_,bb0); MFM((MH)*4+2,1,a2_,bb1); MFM((MH)*4+2,2,a2_,bb2); MFM((MH)*4+2,3,a2_,bb3); \
    MFM((MH)*4+3,0,a3_,bb0); MFM((MH)*4+3,1,a3_,bb1); MFM((MH)*4+3,2,a3_,bb2); MFM((MH)*4+3,3,a3_,bb3); \
    __builtin_amdgcn_s_setprio(0); \
    WAITVM(EVN); \
    __builtin_amdgcn_s_barrier(); \
} while (0)

#define ITER(CUR,J,ISSA,ISSW,DOCVT,W0,W1,W2,W3,EV3) do { \
    PH(CUR,0,0,0,1,f0a,f0b,ISSA,ISSW,DOCVT,W0,63,J); \
    PH(CUR,0,1,1,0,f1a,f1b,ISSA,ISSW,DOCVT,W1,63,J); \
    PH(CUR,1,0,2,1,f2a,f2b,0,   ISSW,DOCVT,W2,63,J); \
    PH(CUR,1,1,3,0,f3a,f3b,0,   ISSW,DOCVT,W3,EV3,J); \
} while (0)

    #pragma unroll 1
    for (int j = 0; j < 30; ++j)
        ITER((j & 1), j, 1, 1, 1, 6, 8, 10, 10, 4);
    ITER(0, 30, 1, 0, 1, 6, 8, 6, 4, 0);      // no new W loads (K ends)
    ITER(1, 31, 0, 0, 0, 63, 63, 63, 63, 63); // compute only

    // ---- epilogue: softcap, z_y scatter, per-row partial sumexp/sumlogit ----
    // C/D layout (m89/m91): col = lane&15, row = (lane>>4)*4 + j
    #pragma unroll
    for (int m = 0; m < 8; ++m)
        #pragma unroll
        for (int n = 0; n < 4; ++n)
            #pragma unroll
            for (int j = 0; j < 4; ++j) {
                float v = acc[m][n][j];
                float e = __expf(v * (1.0f / 15.0f));           // e^{2v/30}
                acc[m][n][j] = SOFTCAP_F - 60.0f / (e + 1.0f);  // 30*tanh(v/30)
            }

    const int colw0 = col0 + wn * 64;
    #pragma unroll
    for (int m = 0; m < 8; ++m) {
        #pragma unroll
        for (int j = 0; j < 4; ++j) {
            const int grow = row0 + wm * 128 + m * 16 + lkg * 4 + j;
            int ty = y[grow];
            int tc = ty - colw0;
            if ((unsigned)tc < 64u && (tc & 15) == lrow) {
                int nt = tc >> 4;
                float zv = (nt == 0) ? acc[m][0][j] :
                           (nt == 1) ? acc[m][1][j] :
                           (nt == 2) ? acc[m][2][j] : acc[m][3][j];
                ws_zy[grow] = zv;
            }
            float se = 0.f, sl = 0.f;
            #pragma unroll
            for (int n = 0; n < 4; ++n) {
                float v = acc[m][n][j];
                sl += v;
                se += __expf(v);     // |logits| <= 30 -> no max-shift needed
            }
            #pragma unroll
            for (int d = 1; d < 16; d <<= 1) {
                se += __shfl_xor(se, d, 64);
                sl += __shfl_xor(sl, d, 64);
            }
            if (lrow == 0) {
                atomicAdd(&ws_se[grow], se);
                atomicAdd(&ws_sl[grow], sl);
            }
        }
    }
}

// ---------------- finalize: per-token loss + mean ----------------
__global__ void finalize_kernel(const float* __restrict__ ws_se,
                                const float* __restrict__ ws_sl,
                                const float* __restrict__ ws_zy,
                                const int* __restrict__ y,
                                float* __restrict__ out, int n)
{
    __shared__ float sL[16], sC[16];
    const int tid = threadIdx.x;
    float loss = 0.f, cnt = 0.f;
    if (tid < n) {
        int ty = y[tid];
        if (ty != IGNORE_IDX) {
            float lse = logf(ws_se[tid]);
            float ce  = lse - (1.0f - LS_EPS) * ws_zy[tid]
                          - (LS_EPS / (float)VV) * ws_sl[tid];
            loss = ce + ZLOSS_SCALE * lse * lse;
            cnt  = 1.f;
        }
    }
    #pragma unroll
    for (int d = 32; d >= 1; d >>= 1) {
        loss += __shfl_down(loss, d, 64);
        cnt  += __shfl_down(cnt,  d, 64);
    }
    const int w = tid >> 6;
    if ((tid & 63) == 0) { sL[w] = loss; sC[w] = cnt; }
    __syncthreads();
    if (tid == 0) {
        float L = 0.f, C = 0.f;
        #pragma unroll
        for (int i = 0; i < 16; ++i) { L += sL[i]; C += sC[i]; }
        out[0] = L / fmaxf(C, 1.0f);
    }
}

extern "C" void kernel_launch(void* const* d_in, const int* in_sizes, int n_in,
                              void* d_out, int out_size, void* d_ws, size_t ws_size,
                              hipStream_t stream) {
    const float* x = (const float*)d_in[0];
    const float* W = (const float*)d_in[1];
    const int*   y = (const int*)d_in[2];
    float* out = (float*)d_out;

    char*  ws    = (char*)d_ws;
    float* ws_se = (float*)(ws);            // [1024] sumexp
    float* ws_sl = (float*)(ws + 4096);     // [1024] sumlogit
    float* ws_zy = (float*)(ws + 8192);     // [1024] target logit
    short* xb    = (short*)(ws + 16384);    // [1024*2048] bf16 x

    hipMemsetAsync(ws, 0, 12288, stream);

    int n4 = (NROWS * H_K) / 4;
    cvt_x_kernel<<<(n4 + 255) / 256, 256, 0, stream>>>(x, xb, n4);

    int grid = (VV / BN) * (NROWS / BM);    // 501 * 4 = 2004
    gemm_fused<<<grid, THREADS, 0, stream>>>(W, xb, y, ws_se, ws_sl, ws_zy);

    finalize_kernel<<<1, 1024, 0, stream>>>(ws_se, ws_sl, ws_zy, y, out, NROWS);
}